// Round 2
// baseline (296.644 us; speedup 1.0000x reference)
//
#include <hip/hip_runtime.h>

static constexpr int B_   = 2;
static constexpr int H_   = 48;
static constexpr int W_   = 48;
static constexpr int C_   = 512;
static constexpr int NH_  = 8;
static constexpr int HD_  = 64;   // head dim
static constexpr int KW_  = 7;    // kernel window
static constexpr int KK2_ = KW_ * KW_;  // 49
static constexpr int ROWS_ = B_ * H_ * W_;   // 4608
static constexpr int QKVN_ = 3 * C_;         // 1536

// C[m][n] = (sum_k A[m][k] * Wt[n][k] + bias[n]) * (n < scale_nlim ? scale : 1)
// A: M x K fp32 row-major. Wt: N x K fp32 row-major. C: M x N fp32.
// Tile: BM=64, BN=64, BK=16; 256 threads; 4x4 micro-tile per thread.
__global__ __launch_bounds__(256)
void gemm_bt_kernel(const float* __restrict__ A, const float* __restrict__ Wt,
                    const float* __restrict__ bias, float* __restrict__ C,
                    int M, int N, int K, float scale, int scale_nlim)
{
    constexpr int BM = 64, BN = 64, BK = 16;
    __shared__ float As[BK][BM];   // transposed: As[k][m]
    __shared__ float Bs[BK][BN];   // transposed: Bs[k][n]

    const int tid = threadIdx.x;
    const int bm = blockIdx.y * BM;
    const int bn = blockIdx.x * BN;
    const int tx = tid & 15;       // 0..15 -> n group
    const int ty = tid >> 4;       // 0..15 -> m group
    const int lrow = tid >> 2;     // 0..63  staging row
    const int lk4  = (tid & 3) * 4;// 0,4,8,12 staging k offset

    float acc[4][4] = {};

    const float* Ap = A  + (size_t)(bm + lrow) * K + lk4;
    const float* Wp = Wt + (size_t)(bn + lrow) * K + lk4;

    for (int k0 = 0; k0 < K; k0 += BK) {
        const float4 af = *reinterpret_cast<const float4*>(Ap + k0);
        const float4 wf = *reinterpret_cast<const float4*>(Wp + k0);
        __syncthreads();   // previous iter's LDS reads complete before overwrite
        As[lk4 + 0][lrow] = af.x;
        As[lk4 + 1][lrow] = af.y;
        As[lk4 + 2][lrow] = af.z;
        As[lk4 + 3][lrow] = af.w;
        Bs[lk4 + 0][lrow] = wf.x;
        Bs[lk4 + 1][lrow] = wf.y;
        Bs[lk4 + 2][lrow] = wf.z;
        Bs[lk4 + 3][lrow] = wf.w;
        __syncthreads();
        #pragma unroll
        for (int kk = 0; kk < BK; ++kk) {
            float4 a = *reinterpret_cast<const float4*>(&As[kk][ty * 4]);
            float4 b = *reinterpret_cast<const float4*>(&Bs[kk][tx * 4]);
            float av[4] = {a.x, a.y, a.z, a.w};
            float bv[4] = {b.x, b.y, b.z, b.w};
            #pragma unroll
            for (int i = 0; i < 4; ++i)
                #pragma unroll
                for (int j = 0; j < 4; ++j)
                    acc[i][j] = fmaf(av[i], bv[j], acc[i][j]);
        }
    }

    // epilogue: bias, optional scale, fp32 store (float4 per row)
    const int n0 = bn + tx * 4;
    const float4 bf = *reinterpret_cast<const float4*>(bias + n0);
    float s0 = (n0 + 0 < scale_nlim) ? scale : 1.0f;
    float s1 = (n0 + 1 < scale_nlim) ? scale : 1.0f;
    float s2 = (n0 + 2 < scale_nlim) ? scale : 1.0f;
    float s3 = (n0 + 3 < scale_nlim) ? scale : 1.0f;
    #pragma unroll
    for (int i = 0; i < 4; ++i) {
        const int m = bm + ty * 4 + i;
        float4 st;
        st.x = (acc[i][0] + bf.x) * s0;
        st.y = (acc[i][1] + bf.y) * s1;
        st.z = (acc[i][2] + bf.z) * s2;
        st.w = (acc[i][3] + bf.w) * s3;
        *reinterpret_cast<float4*>(C + (size_t)m * N + n0) = st;
    }
}

// One block (64 threads = 1 wave) per (pixel, head).
// qkv layout per row (b*H+i)*W+j: [3][NH][HD] -> q at s=0 (pre-scaled), k at s=1, v at s=2.
__global__ __launch_bounds__(64)
void attn_kernel(const float* __restrict__ qkv, float* __restrict__ attn_out)
{
    int bid = blockIdx.x;
    const int h = bid % NH_;  bid /= NH_;
    const int j = bid % W_;   bid /= W_;
    const int i = bid % H_;   bid /= H_;
    const int b = bid;
    const int lane = threadIdx.x;

    const int si = min(max(i - KW_ / 2, 0), H_ - KW_);
    const int sj = min(max(j - KW_ / 2, 0), W_ - KW_);

    __shared__ float qs[HD_];
    __shared__ float attn_sh[KK2_];
    __shared__ int   poff[KK2_];

    const int row = (b * H_ + i) * W_ + j;
    const float* qptr = qkv + (size_t)row * QKVN_ + h * HD_;
    qs[lane] = qptr[lane];
    if (lane < KK2_) {
        const int p = lane / KW_, q = lane % KW_;
        poff[lane] = (b * H_ + (si + p)) * W_ + (sj + q);
    }
    __syncthreads();

    // phase 1: logits = q . k over HD, one neighbor per lane (lanes 0..48)
    float logit = -1e30f;
    if (lane < KK2_) {
        const float* kptr = qkv + (size_t)poff[lane] * QKVN_ + C_ + h * HD_;
        float acc = 0.f;
        #pragma unroll
        for (int d = 0; d < HD_; d += 4) {
            const float4 kf = *reinterpret_cast<const float4*>(kptr + d);
            const float4 qv = *reinterpret_cast<const float4*>(&qs[d]);
            acc += qv.x * kf.x + qv.y * kf.y + qv.z * kf.z + qv.w * kf.w;
        }
        logit = acc;
    }

    // wave-wide softmax over 64 lanes (lanes >=49 hold -inf / 0)
    float m = logit;
    #pragma unroll
    for (int off = 32; off > 0; off >>= 1)
        m = fmaxf(m, __shfl_xor(m, off));
    float e = (lane < KK2_) ? __expf(logit - m) : 0.f;
    float s = e;
    #pragma unroll
    for (int off = 32; off > 0; off >>= 1)
        s += __shfl_xor(s, off);
    if (lane < KK2_) attn_sh[lane] = e / s;
    __syncthreads();

    // phase 2: out[d] = sum_p attn[p] * v[p][d], one d per lane
    float acc = 0.f;
    #pragma unroll
    for (int p = 0; p < KK2_; ++p) {
        const float* vptr = qkv + (size_t)poff[p] * QKVN_ + 2 * C_ + h * HD_;
        acc = fmaf(attn_sh[p], vptr[lane], acc);
    }
    attn_out[(size_t)row * C_ + h * HD_ + lane] = acc;
}

extern "C" void kernel_launch(void* const* d_in, const int* in_sizes, int n_in,
                              void* d_out, int out_size, void* d_ws, size_t ws_size,
                              hipStream_t stream)
{
    const float* x      = (const float*)d_in[0];
    const float* qkv_w  = (const float*)d_in[1];
    const float* qkv_b  = (const float*)d_in[2];
    const float* proj_w = (const float*)d_in[3];
    const float* proj_b = (const float*)d_in[4];
    float* out = (float*)d_out;

    float* qkv      = (float*)d_ws;
    float* attn_out = (float*)((char*)d_ws + (size_t)ROWS_ * QKVN_ * sizeof(float));

    // 1) QKV = x @ qkv_w.T + qkv_b ; q-part (n<512) scaled by hd^-0.5 = 0.125
    gemm_bt_kernel<<<dim3(QKVN_ / 64, ROWS_ / 64), 256, 0, stream>>>(
        x, qkv_w, qkv_b, qkv, ROWS_, QKVN_, C_, 0.125f, C_);

    // 2) neighborhood attention
    attn_kernel<<<dim3(B_ * H_ * W_ * NH_), 64, 0, stream>>>(qkv, attn_out);

    // 3) out = attn_out @ proj_w.T + proj_b
    gemm_bt_kernel<<<dim3(C_ / 64, ROWS_ / 64), 256, 0, stream>>>(
        attn_out, proj_w, proj_b, out, ROWS_, C_, C_, 1.0f, 0);
}

// Round 3
// 154.250 us; speedup vs baseline: 1.9231x; 1.9231x over previous
//
#include <hip/hip_runtime.h>

typedef __bf16 bf16_t;
typedef __bf16 bf16x8 __attribute__((ext_vector_type(8)));
typedef __bf16 bf16x4 __attribute__((ext_vector_type(4)));
typedef float  f32x4  __attribute__((ext_vector_type(4)));

static constexpr int B_   = 2;
static constexpr int H_   = 48;
static constexpr int W_   = 48;
static constexpr int C_   = 512;
static constexpr int NH_  = 8;
static constexpr int HD_  = 64;
static constexpr int KW_  = 7;
static constexpr int KK2_ = KW_ * KW_;        // 49
static constexpr int ROWS_ = B_ * H_ * W_;    // 4608
static constexpr int QKVN_ = 3 * C_;          // 1536

// async global->LDS, 16B per lane; LDS dest = wave-uniform base + lane*16
#define GLDS16(g, l) __builtin_amdgcn_global_load_lds(                       \
    (const __attribute__((address_space(1))) void*)(g),                      \
    (__attribute__((address_space(3))) void*)(l), 16, 0, 0)

// fp32 -> bf16 pre-convert for x, qkv_w, proj_w (one grid-stride-free pass)
__global__ __launch_bounds__(256)
void convert_kernel(const float* __restrict__ x,  const float* __restrict__ qw,
                    const float* __restrict__ pw,
                    bf16_t* __restrict__ xb, bf16_t* __restrict__ qwb,
                    bf16_t* __restrict__ pwb)
{
    constexpr int NX = ROWS_ * C_;     // 2359296
    constexpr int NQ = QKVN_ * C_;     // 786432
    constexpr int NP = C_ * C_;        // 262144
    const int idx = (blockIdx.x * 256 + threadIdx.x) * 4;
    if (idx >= NX + NQ + NP) return;
    const float* src; bf16_t* dst; int off;
    if (idx < NX)           { src = x;  dst = xb;  off = idx; }
    else if (idx < NX + NQ) { src = qw; dst = qwb; off = idx - NX; }
    else                    { src = pw; dst = pwb; off = idx - NX - NQ; }
    const float4 v = *reinterpret_cast<const float4*>(src + off);
    bf16x4 o;
    o[0] = (bf16_t)v.x; o[1] = (bf16_t)v.y; o[2] = (bf16_t)v.z; o[3] = (bf16_t)v.w;
    *reinterpret_cast<bf16x4*>(dst + off) = o;
}

// C[m][n] = (sum_k A[m][k]*Wt[n][k] + bias[n]) * (n < scale_nlim ? scale : 1)
// A: MxK bf16 row-major. Wt: NxK bf16 row-major (B^T form). bias fp32.
// 128x128 tile, BK=32, 256 threads = 4 waves, each wave 64x64 via 4x4 MFMA
// tiles of v_mfma_f32_16x16x32_bf16. m97-class structure.
template <typename OutT>
__global__ __launch_bounds__(256)
void gemm_mfma_kernel(const bf16_t* __restrict__ A, const bf16_t* __restrict__ Wt,
                      const float* __restrict__ bias, OutT* __restrict__ C,
                      int M, int N, int K, float scale, int scale_nlim)
{
    constexpr int BM = 128, BN = 128, BK = 32;
    __shared__ bf16_t Al[BM * BK];   // [row][k], 64 B/row, no padding (GLDS layout)
    __shared__ bf16_t Bl[BN * BK];

    const int tid  = threadIdx.x;
    const int wave = tid >> 6;
    const int lane = tid & 63;
    const int bm = blockIdx.y * BM;
    const int bn = blockIdx.x * BN;
    const int wm = (wave >> 1) * 64;   // wave tile row origin in block tile
    const int wn = (wave & 1) * 64;    // wave tile col origin

    f32x4 acc[4][4] = {};

    // staging: per K-tile, each wave loads 16 rows of A (2 issues: +0, +64 rows)
    // lane l -> row wave*16 + (l>>2), k-chunk (l&3)*8  => LDS offset l*16 B
    const int srow  = wave * 16 + (lane >> 2);
    const int skoff = (lane & 3) * 8;
    const bf16_t* Ag0 = A  + (size_t)(bm + srow) * K + skoff;
    const bf16_t* Ag1 = A  + (size_t)(bm + 64 + srow) * K + skoff;
    const bf16_t* Bg0 = Wt + (size_t)(bn + srow) * K + skoff;
    const bf16_t* Bg1 = Wt + (size_t)(bn + 64 + srow) * K + skoff;
    bf16_t* Al0 = &Al[(wave * 16) * BK];
    bf16_t* Al1 = &Al[(64 + wave * 16) * BK];
    bf16_t* Bl0 = &Bl[(wave * 16) * BK];
    bf16_t* Bl1 = &Bl[(64 + wave * 16) * BK];

    // fragment read bases: A[m = wm + i*16 + (lane&15)][k = (lane>>4)*8 + j]
    const int lm = lane & 15;
    const int lk = (lane >> 4) * 8;
    const bf16_t* Afrag = &Al[(wm + lm) * BK + lk];
    const bf16_t* Bfrag = &Bl[(wn + lm) * BK + lk];

    for (int k0 = 0; k0 < K; k0 += BK) {
        __syncthreads();               // previous iter's LDS reads complete
        GLDS16(Ag0 + k0, Al0);
        GLDS16(Ag1 + k0, Al1);
        GLDS16(Bg0 + k0, Bl0);
        GLDS16(Bg1 + k0, Bl1);
        __syncthreads();               // drains vmcnt, LDS tiles ready

        bf16x8 ar[4], br[4];
        #pragma unroll
        for (int i = 0; i < 4; ++i)
            ar[i] = *reinterpret_cast<const bf16x8*>(Afrag + i * 16 * BK);
        #pragma unroll
        for (int j = 0; j < 4; ++j)
            br[j] = *reinterpret_cast<const bf16x8*>(Bfrag + j * 16 * BK);
        #pragma unroll
        for (int i = 0; i < 4; ++i)
            #pragma unroll
            for (int j = 0; j < 4; ++j)
                acc[i][j] = __builtin_amdgcn_mfma_f32_16x16x32_bf16(
                    ar[i], br[j], acc[i][j], 0, 0, 0);
    }

    // epilogue: C/D layout col = lane&15, row = (lane>>4)*4 + reg  [m89/m91]
    const int rowq = (lane >> 4) * 4;
    #pragma unroll
    for (int j = 0; j < 4; ++j) {
        const int col = bn + wn + j * 16 + lm;
        const float bv = bias[col];
        const float sc = (col < scale_nlim) ? scale : 1.0f;
        #pragma unroll
        for (int i = 0; i < 4; ++i) {
            const int row0 = bm + wm + i * 16 + rowq;
            #pragma unroll
            for (int r = 0; r < 4; ++r) {
                const float v = (acc[i][j][r] + bv) * sc;
                C[(size_t)(row0 + r) * N + col] = (OutT)v;
            }
        }
    }
}

// One wave per (pixel, head). qkv row layout: [3][NH][HD], q pre-scaled.
__global__ __launch_bounds__(64)
void attn_kernel(const bf16_t* __restrict__ qkv, bf16_t* __restrict__ attn_out)
{
    int bid = blockIdx.x;
    const int h = bid & (NH_ - 1);  bid >>= 3;
    const int j = bid % W_;         bid /= W_;
    const int i = bid % H_;         bid /= H_;
    const int b = bid;
    const int lane = threadIdx.x;

    const int si = min(max(i - KW_ / 2, 0), H_ - KW_);
    const int sj = min(max(j - KW_ / 2, 0), W_ - KW_);

    __shared__ float qs[HD_];
    __shared__ float attn_sh[KK2_];
    __shared__ int   poff[64];

    const int row = (b * H_ + i) * W_ + j;
    qs[lane] = (float)qkv[(size_t)row * QKVN_ + h * HD_ + lane];
    if (lane < KK2_)
        poff[lane] = (b * H_ + (si + lane / KW_)) * W_ + (sj + lane % KW_);
    __syncthreads();

    // logits: one neighbor per lane (lanes 0..48)
    float logit = -1e30f;
    if (lane < KK2_) {
        const bf16_t* kptr = qkv + (size_t)poff[lane] * QKVN_ + C_ + h * HD_;
        float acc = 0.f;
        #pragma unroll
        for (int d = 0; d < HD_; d += 8) {
            const bf16x8 kv = *reinterpret_cast<const bf16x8*>(kptr + d);
            #pragma unroll
            for (int u = 0; u < 8; ++u)
                acc = fmaf(qs[d + u], (float)kv[u], acc);
        }
        logit = acc;
    }

    // wave-wide softmax over 64 lanes
    float m = logit;
    #pragma unroll
    for (int off = 32; off > 0; off >>= 1)
        m = fmaxf(m, __shfl_xor(m, off));
    float e = (lane < KK2_) ? __expf(logit - m) : 0.f;
    float s = e;
    #pragma unroll
    for (int off = 32; off > 0; off >>= 1)
        s += __shfl_xor(s, off);
    if (lane < KK2_) attn_sh[lane] = e / s;
    __syncthreads();

    // out[d] = sum_p attn[p] * v[p][d]; one d per lane
    float acc = 0.f;
    #pragma unroll
    for (int p = 0; p < KK2_; ++p) {
        const bf16_t* vptr = qkv + (size_t)poff[p] * QKVN_ + 2 * C_ + h * HD_;
        acc = fmaf(attn_sh[p], (float)vptr[lane], acc);
    }
    attn_out[(size_t)row * C_ + h * HD_ + lane] = (bf16_t)acc;
}

extern "C" void kernel_launch(void* const* d_in, const int* in_sizes, int n_in,
                              void* d_out, int out_size, void* d_ws, size_t ws_size,
                              hipStream_t stream)
{
    const float* x      = (const float*)d_in[0];
    const float* qkv_w  = (const float*)d_in[1];
    const float* qkv_b  = (const float*)d_in[2];
    const float* proj_w = (const float*)d_in[3];
    const float* proj_b = (const float*)d_in[4];
    float* out = (float*)d_out;

    char* w = (char*)d_ws;
    bf16_t* xb    = (bf16_t*)w;  w += (size_t)ROWS_ * C_ * 2;
    bf16_t* qwb   = (bf16_t*)w;  w += (size_t)QKVN_ * C_ * 2;
    bf16_t* pwb   = (bf16_t*)w;  w += (size_t)C_ * C_ * 2;
    bf16_t* qkvb  = (bf16_t*)w;  w += (size_t)ROWS_ * QKVN_ * 2;
    bf16_t* attnb = (bf16_t*)w;

    // 0) fp32 -> bf16 casts of x and both weight matrices
    constexpr int TOT4 = (ROWS_ * C_ + QKVN_ * C_ + C_ * C_) / 4;
    convert_kernel<<<(TOT4 + 255) / 256, 256, 0, stream>>>(x, qkv_w, proj_w, xb, qwb, pwb);

    // 1) QKV = x @ qkv_w.T + qkv_b ; q-part (n<512) scaled by 0.125
    gemm_mfma_kernel<bf16_t><<<dim3(QKVN_ / 128, ROWS_ / 128), 256, 0, stream>>>(
        xb, qwb, qkv_b, qkvb, ROWS_, QKVN_, C_, 0.125f, C_);

    // 2) neighborhood attention
    attn_kernel<<<dim3(B_ * H_ * W_ * NH_), 64, 0, stream>>>(qkvb, attnb);

    // 3) out = attn_out @ proj_w.T + proj_b (fp32 output)
    gemm_mfma_kernel<float><<<dim3(C_ / 128, ROWS_ / 128), 256, 0, stream>>>(
        attnb, pwb, proj_b, out, ROWS_, C_, C_, 1.0f, 0);
}

// Round 4
// 111.493 us; speedup vs baseline: 2.6606x; 1.3835x over previous
//
#include <hip/hip_runtime.h>

typedef __bf16 bf16_t;
typedef __bf16 bf16x8 __attribute__((ext_vector_type(8)));
typedef __bf16 bf16x4 __attribute__((ext_vector_type(4)));
typedef float  f32x4  __attribute__((ext_vector_type(4)));

static constexpr int B_   = 2;
static constexpr int H_   = 48;
static constexpr int W_   = 48;
static constexpr int C_   = 512;
static constexpr int NH_  = 8;
static constexpr int HD_  = 64;
static constexpr int KW_  = 7;
static constexpr int ROWS_ = B_ * H_ * W_;    // 4608
static constexpr int QKVN_ = 3 * C_;          // 1536

// async global->LDS, 16B per lane; LDS dest = wave-uniform base + lane*16
#define GLDS16(g, l) __builtin_amdgcn_global_load_lds(                       \
    (const __attribute__((address_space(1))) void*)(g),                      \
    (__attribute__((address_space(3))) void*)(l), 16, 0, 0)

// fp32 -> bf16 pre-convert for x, qkv_w, proj_w
__global__ __launch_bounds__(256)
void convert_kernel(const float* __restrict__ x,  const float* __restrict__ qw,
                    const float* __restrict__ pw,
                    bf16_t* __restrict__ xb, bf16_t* __restrict__ qwb,
                    bf16_t* __restrict__ pwb)
{
    constexpr int NX = ROWS_ * C_;
    constexpr int NQ = QKVN_ * C_;
    constexpr int NP = C_ * C_;
    const int idx = (blockIdx.x * 256 + threadIdx.x) * 4;
    if (idx >= NX + NQ + NP) return;
    const float* src; bf16_t* dst; int off;
    if (idx < NX)           { src = x;  dst = xb;  off = idx; }
    else if (idx < NX + NQ) { src = qw; dst = qwb; off = idx - NX; }
    else                    { src = pw; dst = pwb; off = idx - NX - NQ; }
    const float4 v = *reinterpret_cast<const float4*>(src + off);
    bf16x4 o;
    o[0] = (bf16_t)v.x; o[1] = (bf16_t)v.y; o[2] = (bf16_t)v.z; o[3] = (bf16_t)v.w;
    *reinterpret_cast<bf16x4*>(dst + off) = o;
}

// C[m][n] = (sum_k A[m][k]*Wt[n][k] + bias[n]) * (n < scale_nlim ? scale : 1)
// BK=64, 256 threads = 4 waves in (BM/(WMT*16)) x (BN/(WNT*16)) grid.
// LDS rows of 64 bf16 (8 chunks of 16B), chunk slot s holds global chunk
// s ^ (row&7)  -> b128 frag reads hit the bank floor.
template<int BM, int BN, int WMT, int WNT, typename OutT>
__global__ __launch_bounds__(256)
void gemm_bt(const bf16_t* __restrict__ A, const bf16_t* __restrict__ Wt,
             const float* __restrict__ bias, OutT* __restrict__ C,
             int M, int N, int K, float scale, int scale_nlim)
{
    constexpr int BK = 64;
    constexpr int WCOLS = BN / (WNT * 16);
    __shared__ bf16_t Al[BM * BK];
    __shared__ bf16_t Bl[BN * BK];

    const int tid  = threadIdx.x;
    const int wave = tid >> 6;
    const int lane = tid & 63;
    const int bm = blockIdx.y * BM;
    const int bn = blockIdx.x * BN;
    const int wm = (wave / WCOLS) * (WMT * 16);
    const int wn = (wave % WCOLS) * (WNT * 16);
    const int n15 = lane & 15, q4 = lane >> 4, x7 = lane & 7;
    const int srow = lane >> 3, schunk = lane & 7;

    f32x4 acc[WMT][WNT] = {};

    for (int k0 = 0; k0 < K; k0 += BK) {
        __syncthreads();
        for (int i = wave; i < BM / 8; i += 4) {
            const int row = i * 8 + srow;
            const int cg = schunk ^ (row & 7);
            GLDS16(A + (size_t)(bm + row) * K + k0 + cg * 8, Al + i * 512);
        }
        for (int i = wave; i < BN / 8; i += 4) {
            const int row = i * 8 + srow;
            const int cg = schunk ^ (row & 7);
            GLDS16(Wt + (size_t)(bn + row) * K + k0 + cg * 8, Bl + i * 512);
        }
        __syncthreads();

        #pragma unroll
        for (int ks = 0; ks < 2; ++ks) {
            const int cl = (ks * 4 + q4) ^ x7;
            bf16x8 a[WMT], b[WNT];
            #pragma unroll
            for (int it = 0; it < WMT; ++it)
                a[it] = *reinterpret_cast<const bf16x8*>(Al + (wm + it * 16 + n15) * 64 + cl * 8);
            #pragma unroll
            for (int jt = 0; jt < WNT; ++jt)
                b[jt] = *reinterpret_cast<const bf16x8*>(Bl + (wn + jt * 16 + n15) * 64 + cl * 8);
            #pragma unroll
            for (int it = 0; it < WMT; ++it)
                #pragma unroll
                for (int jt = 0; jt < WNT; ++jt)
                    acc[it][jt] = __builtin_amdgcn_mfma_f32_16x16x32_bf16(
                        a[it], b[jt], acc[it][jt], 0, 0, 0);
        }
    }

    // epilogue: C/D layout col = lane&15, row = (lane>>4)*4 + r
    #pragma unroll
    for (int jt = 0; jt < WNT; ++jt) {
        const int col = bn + wn + jt * 16 + n15;
        const float bv = bias[col];
        const float sc = (col < scale_nlim) ? scale : 1.0f;
        #pragma unroll
        for (int it = 0; it < WMT; ++it) {
            const int row0 = bm + wm + it * 16 + q4 * 4;
            #pragma unroll
            for (int r = 0; r < 4; ++r)
                C[(size_t)(row0 + r) * N + col] = (OutT)((acc[it][jt][r] + bv) * sc);
        }
    }
}

// ---------------- MFMA neighborhood attention ----------------
// One block per (b, 8x8 pixel tile, head). 256 threads = 4 waves.
// Union K/V window = 14x14 = 196 pixels (staged rows 0..207, clamped).
// S = Q.K^T (64 pix x 208 win), mask to each pixel's 7x7, softmax, P.V.
static constexpr int WIN  = 196;   // real window pixels
static constexpr int WROW = 208;   // staged K rows (13 n-tiles * 16)
static constexpr int PST  = 232;   // P / V^T row stride (224 + 8 pad)
static constexpr int KBYTES = WROW * 64 * 2;       // 26624
static constexpr int PBYTES = 64 * PST * 2;        // 29696 (union w/ K)
static constexpr int VTBYTES = 64 * PST * 2;       // 29696

__global__ __launch_bounds__(256)
void attn_mfma_kernel(const bf16_t* __restrict__ qkv, bf16_t* __restrict__ attn_out)
{
    int bid = blockIdx.x;
    const int h  = bid & 7;   bid >>= 3;
    const int tj = bid % 6;   bid /= 6;
    const int ti = bid % 6;   bid /= 6;
    const int b  = bid;

    const int tid = threadIdx.x;
    const int wave = tid >> 6;
    const int lane = tid & 63;
    const int n15 = lane & 15, q4 = lane >> 4, x7 = lane & 7;

    const int gi0 = ti * 8, gj0 = tj * 8;
    const int si0 = min(max(gi0 - 3, 0), H_ - 14);
    const int sj0 = min(max(gj0 - 3, 0), W_ - 14);

    __shared__ char smem[PBYTES + VTBYTES + 256];
    bf16_t* Kl   = (bf16_t*)smem;              // [208][64], xor-swizzled chunks
    bf16_t* P    = (bf16_t*)smem;              // [64][232]  (aliases Kl)
    bf16_t* VT   = (bf16_t*)(smem + PBYTES);   // [64][232]  V transposed
    float*  invs = (float*)(smem + PBYTES + VTBYTES);

    // ---- stage K (global_load_lds, swizzled), rows 0..207 ----
    for (int i = wave; i < WROW / 8; i += 4) {
        const int wrow = i * 8 + (lane >> 3);
        const int wc_r = min(wrow, WIN - 1);                  // clamp pad rows
        const unsigned wr = ((unsigned)wc_r * 4682u) >> 16;   // /14
        const unsigned wc = (unsigned)wc_r - wr * 14u;
        const int gp = (b * H_ + si0 + (int)wr) * W_ + sj0 + (int)wc;
        const int cg = (lane & 7) ^ (wrow & 7);
        GLDS16(qkv + (size_t)gp * QKVN_ + C_ + h * HD_ + cg * 8, Kl + i * 512);
    }

    // ---- stage V transposed: VT[d][w] ----
    for (int t = tid; t < WIN * 8; t += 256) {
        const int w = t % WIN, c = t / WIN;
        const unsigned wr = ((unsigned)w * 4682u) >> 16;
        const unsigned wc = (unsigned)w - wr * 14u;
        const int gp = (b * H_ + si0 + (int)wr) * W_ + sj0 + (int)wc;
        const bf16x8 v8 = *reinterpret_cast<const bf16x8*>(
            qkv + (size_t)gp * QKVN_ + 2 * C_ + h * HD_ + c * 8);
        #pragma unroll
        for (int u = 0; u < 8; ++u)
            VT[(c * 8 + u) * PST + w] = v8[u];
    }
    // zero VT cols 196..223 (padding consumed by the PV K-loop)
    for (int t = tid; t < 64 * 7; t += 256) {
        const int d = t / 7, k = t % 7;
        bf16x4 z = {};
        *reinterpret_cast<bf16x4*>(VT + d * PST + WIN + k * 4) = z;
    }

    // ---- Q fragments straight from global (wave m-tile = pixels wave*16..) ----
    const int pixq = wave * 16 + n15;
    const int gpq = (b * H_ + gi0 + (pixq >> 3)) * W_ + gj0 + (pixq & 7);
    bf16x8 aq[2];
    #pragma unroll
    for (int ks = 0; ks < 2; ++ks)
        aq[ks] = *reinterpret_cast<const bf16x8*>(
            qkv + (size_t)gpq * QKVN_ + h * HD_ + ks * 32 + q4 * 8);

    __syncthreads();   // drains GLDS vmcnt + VT writes

    // ---- S = Q.K^T : 13 n-tiles x 2 k-steps ----
    f32x4 S[13] = {};
    #pragma unroll
    for (int j = 0; j < 13; ++j) {
        #pragma unroll
        for (int ks = 0; ks < 2; ++ks) {
            const int cl = (ks * 4 + q4) ^ x7;
            const bf16x8 bk = *reinterpret_cast<const bf16x8*>(
                Kl + (j * 16 + n15) * 64 + cl * 8);
            S[j] = __builtin_amdgcn_mfma_f32_16x16x32_bf16(aq[ks], bk, S[j], 0, 0, 0);
        }
    }

    // ---- mask to each pixel's 7x7 window ----
    int ri[4], cj[4];
    #pragma unroll
    for (int r = 0; r < 4; ++r) {
        const int pix = wave * 16 + q4 * 4 + r;
        const int gi = gi0 + (pix >> 3), gj = gj0 + (pix & 7);
        ri[r] = min(max(gi - 3, 0), H_ - KW_) - si0;
        cj[r] = min(max(gj - 3, 0), W_ - KW_) - sj0;
    }
    #pragma unroll
    for (int j = 0; j < 13; ++j) {
        const unsigned w = j * 16 + n15;
        const unsigned wr = (w * 4682u) >> 16;
        const unsigned wc = w - wr * 14u;
        #pragma unroll
        for (int r = 0; r < 4; ++r) {
            const bool valid = ((unsigned)(wr - ri[r]) < 7u) &&
                               ((unsigned)(wc - cj[r]) < 7u);
            S[j][r] = valid ? S[j][r] : -1e30f;
        }
    }

    // ---- softmax per row (each wave owns its 16 rows entirely) ----
    float mx[4], sm[4];
    #pragma unroll
    for (int r = 0; r < 4; ++r) {
        float m = S[0][r];
        #pragma unroll
        for (int j = 1; j < 13; ++j) m = fmaxf(m, S[j][r]);
        #pragma unroll
        for (int off = 1; off < 16; off <<= 1) m = fmaxf(m, __shfl_xor(m, off));
        mx[r] = m;
    }
    #pragma unroll
    for (int j = 0; j < 13; ++j)
        #pragma unroll
        for (int r = 0; r < 4; ++r)
            S[j][r] = __expf(S[j][r] - mx[r]);
    #pragma unroll
    for (int r = 0; r < 4; ++r) {
        float s = S[0][r];
        #pragma unroll
        for (int j = 1; j < 13; ++j) s += S[j][r];
        #pragma unroll
        for (int off = 1; off < 16; off <<= 1) s += __shfl_xor(s, off);
        sm[r] = s;
    }
    if (n15 == 0) {
        #pragma unroll
        for (int r = 0; r < 4; ++r)
            invs[wave * 16 + q4 * 4 + r] = 1.0f / sm[r];
    }

    __syncthreads();   // all waves done reading Kl -> safe to overwrite with P

    // ---- write P (unnormalized probs, bf16) ----
    #pragma unroll
    for (int j = 0; j < 13; ++j)
        #pragma unroll
        for (int r = 0; r < 4; ++r)
            P[(wave * 16 + q4 * 4 + r) * PST + j * 16 + n15] = (bf16_t)S[j][r];
    // zero P cols 208..223
    {
        const int pix = tid >> 2, c4 = (tid & 3) * 4;
        bf16x4 z = {};
        *reinterpret_cast<bf16x4*>(P + pix * PST + 208 + c4) = z;
    }

    __syncthreads();

    // ---- O^T = V^T . P^T via mfma(A=VT row d, B=P row pix) ----
    f32x4 O[4] = {};
    #pragma unroll
    for (int ks = 0; ks < 7; ++ks) {
        const bf16x8 av = *reinterpret_cast<const bf16x8*>(
            VT + (wave * 16 + n15) * PST + ks * 32 + q4 * 8);
        #pragma unroll
        for (int j = 0; j < 4; ++j) {
            const bf16x8 bp = *reinterpret_cast<const bf16x8*>(
                P + (j * 16 + n15) * PST + ks * 32 + q4 * 8);
            O[j] = __builtin_amdgcn_mfma_f32_16x16x32_bf16(av, bp, O[j], 0, 0, 0);
        }
    }

    // ---- epilogue: D[m=d][n=pix]; scale by 1/sum, store 4 bf16 ----
    #pragma unroll
    for (int j = 0; j < 4; ++j) {
        const int pix = j * 16 + n15;
        const float is = invs[pix];
        const int grow = (b * H_ + gi0 + (pix >> 3)) * W_ + gj0 + (pix & 7);
        const int d0 = wave * 16 + q4 * 4;
        bf16x4 o;
        #pragma unroll
        for (int r = 0; r < 4; ++r) o[r] = (bf16_t)(O[j][r] * is);
        *reinterpret_cast<bf16x4*>(attn_out + (size_t)grow * C_ + h * HD_ + d0) = o;
    }
}

extern "C" void kernel_launch(void* const* d_in, const int* in_sizes, int n_in,
                              void* d_out, int out_size, void* d_ws, size_t ws_size,
                              hipStream_t stream)
{
    const float* x      = (const float*)d_in[0];
    const float* qkv_w  = (const float*)d_in[1];
    const float* qkv_b  = (const float*)d_in[2];
    const float* proj_w = (const float*)d_in[3];
    const float* proj_b = (const float*)d_in[4];
    float* out = (float*)d_out;

    char* w = (char*)d_ws;
    bf16_t* xb    = (bf16_t*)w;  w += (size_t)ROWS_ * C_ * 2;
    bf16_t* qwb   = (bf16_t*)w;  w += (size_t)QKVN_ * C_ * 2;
    bf16_t* pwb   = (bf16_t*)w;  w += (size_t)C_ * C_ * 2;
    bf16_t* qkvb  = (bf16_t*)w;  w += (size_t)ROWS_ * QKVN_ * 2;
    bf16_t* attnb = (bf16_t*)w;

    // 0) fp32 -> bf16 casts
    constexpr int TOT4 = (ROWS_ * C_ + QKVN_ * C_ + C_ * C_) / 4;
    convert_kernel<<<(TOT4 + 255) / 256, 256, 0, stream>>>(x, qkv_w, proj_w, xb, qwb, pwb);

    // 1) QKV = x @ qkv_w.T + qkv_b ; q-part scaled by 0.125.  128x64 tiles -> 864 blocks
    gemm_bt<128, 64, 4, 2, bf16_t><<<dim3(QKVN_ / 64, ROWS_ / 128), 256, 0, stream>>>(
        xb, qwb, qkv_b, qkvb, ROWS_, QKVN_, C_, 0.125f, C_);

    // 2) neighborhood attention (MFMA), 2*6*6*8 = 576 blocks
    attn_mfma_kernel<<<dim3(B_ * 6 * 6 * NH_), 256, 0, stream>>>(qkvb, attnb);

    // 3) out = attn @ proj_w.T + proj_b.  64x64 tiles -> 576 blocks
    gemm_bt<64, 64, 2, 2, float><<<dim3(C_ / 64, ROWS_ / 64), 256, 0, stream>>>(
        attnb, pwb, proj_b, out, ROWS_, C_, C_, 1.0f, 0);
}